// Round 20
// baseline (255.215 us; speedup 1.0000x reference)
//
#include <hip/hip_runtime.h>
#include <stdint.h>

typedef _Float16 f16;
typedef __attribute__((ext_vector_type(8))) _Float16 f16x8;
typedef __attribute__((ext_vector_type(4))) float f32x4;

// ---------------- threefry2x32 (JAX partitionable, key=(0,42), counts=(0,i)) ----
__device__ __forceinline__ uint32_t rotl1(uint32_t x, uint32_t n){
  return __builtin_amdgcn_alignbit(x, x, 32u - n);
}
__device__ __forceinline__ uint32_t tf_bits(uint32_t i){
  const uint32_t ks1 = 42u, ks2 = 0x1BD11BDAu ^ 42u;
  uint32_t x0 = 0u, x1 = i + 42u;
#define R4(a,b,c,d) \
  x0 += x1; x1 = rotl1(x1,a); x1 ^= x0; \
  x0 += x1; x1 = rotl1(x1,b); x1 ^= x0; \
  x0 += x1; x1 = rotl1(x1,c); x1 ^= x0; \
  x0 += x1; x1 = rotl1(x1,d); x1 ^= x0;
  R4(13,15,26,6)  x0 += ks1; x1 += ks2 + 1u;
  R4(17,29,16,24) x0 += ks2; x1 += 2u;         // ks0 = 0
  R4(13,15,26,6)               x1 += ks1 + 3u; // x0 += ks0 = +0
  R4(17,29,16,24) x0 += ks1; x1 += ks2 + 4u;
  R4(13,15,26,6)  x0 += ks2; x1 += 5u;         // ks0 = 0
#undef R4
  return x0 ^ x1;
}

// ---------------- K1 (A/B template): R4-exact projections, SPLIT PAIR --------
// (measured ~100-117us combined vs ~151us as a single dispatch)
template<int PACKED>
__global__ __launch_bounds__(256) void proj_kernel(
    const float* __restrict__ query, const float* __restrict__ keyp, const float* __restrict__ value,
    const float* __restrict__ Wq, const float* __restrict__ bq,
    const float* __restrict__ Wk, const float* __restrict__ bk,
    const float* __restrict__ Wv, const float* __restrict__ bv,
    const float* __restrict__ Wo,
    f16* __restrict__ qp, f16* __restrict__ kp, f16* __restrict__ vpT,
    f16* __restrict__ WoT)
{
  __shared__ __align__(16) f16 Alds[64][40];   // rows x k (80B stride)
  __shared__ __align__(16) f16 Wlds[64][40];   // [col][k]
  const int bid = blockIdx.x;
  const int tid = threadIdx.x;
  const int lane = tid & 63, wave = tid >> 6;
  const int llo = lane & 15, lhi = lane >> 4;

  int p;
  if (PACKED == 0){
    if (bid < 256){
      int t = bid*256 + tid;
      int n = t & 1023, k = t >> 10;
      WoT[(long)n*64 + k] = (f16)Wo[(long)k*1024 + n];
      return;
    }
    p = bid - 256;            // [0,768)
  } else {
    p = 768 + bid;            // [768,1536)
  }

  const int which = p >> 9;           // 0..2
  const long m0 = (long)(p & 511) * 64;
  const float* A    = which==0 ? query : (which==1 ? keyp : value);
  const float* W    = which==0 ? Wq    : (which==1 ? Wk   : Wv);
  const float* bias = which==0 ? bq    : (which==1 ? bk   : bv);

  f32x4 acc[4];
  #pragma unroll
  for (int n=0;n<4;n++){
    float bb = bias[16*n + llo];
    acc[n][0]=bb; acc[n][1]=bb; acc[n][2]=bb; acc[n][3]=bb;
  }

  const int ar = tid >> 2;            // 0..63
  const int ac = (tid & 3) * 8;
  const int wcol = tid & 63;
  const int wk = (tid >> 6) * 8;

  for (int k0 = 0; k0 < 1024; k0 += 32){
    {
      const float* asrc = A + (m0 + ar)*1024 + k0 + ac;
      float4 v0 = *(const float4*)asrc;
      float4 v1 = *(const float4*)(asrc + 4);
      if (PACKED == 0){
        f16* ad = &Alds[ar][ac];
        ad[0]=(f16)v0.x; ad[1]=(f16)v0.y; ad[2]=(f16)v0.z; ad[3]=(f16)v0.w;
        ad[4]=(f16)v1.x; ad[5]=(f16)v1.y; ad[6]=(f16)v1.z; ad[7]=(f16)v1.w;
      } else {
        union { f16 h[8]; f16x8 v; } aw;
        aw.h[0]=(f16)v0.x; aw.h[1]=(f16)v0.y; aw.h[2]=(f16)v0.z; aw.h[3]=(f16)v0.w;
        aw.h[4]=(f16)v1.x; aw.h[5]=(f16)v1.y; aw.h[6]=(f16)v1.z; aw.h[7]=(f16)v1.w;
        *(f16x8*)&Alds[ar][ac] = aw.v;
      }
      f16 wt[8];
      #pragma unroll
      for (int j=0;j<8;j++) wt[j] = (f16)W[(long)(k0+wk+j)*64 + wcol];
      *(f16x8*)&Wlds[wcol][wk] = *(f16x8*)wt;
    }
    __syncthreads();
    f16x8 af = *(const f16x8*)&Alds[wave*16 + llo][lhi*8];
    #pragma unroll
    for (int n=0;n<4;n++){
      f16x8 bf = *(const f16x8*)&Wlds[16*n + llo][lhi*8];
      acc[n] = __builtin_amdgcn_mfma_f32_16x16x32_f16(af, bf, acc[n], 0,0,0);
    }
    __syncthreads();
  }

  if (which < 2){
    const float scale = (which==0) ? 2.0f : 1.0f;   // fold dk=2.0 into q
    f16* dst = (which==0) ? qp : kp;
    #pragma unroll
    for (int n=0;n<4;n++)
      #pragma unroll
      for (int j=0;j<4;j++){
        long row = m0 + wave*16 + lhi*4 + j;
        dst[row*64 + 16*n + llo] = (f16)(acc[n][j]*scale);
      }
  } else {
    long row0 = m0 + wave*16 + lhi*4;
    long bh = row0 >> 11;
    long lr = row0 & 2047;
    #pragma unroll
    for (int n=0;n<4;n++){
      union { f16 h[4]; ushort4 u; } pk;
      #pragma unroll
      for (int j=0;j<4;j++) pk.h[j] = (f16)acc[n][j];
      *(ushort4*)&vpT[(bh*64 + 16*n + llo)*2048 + lr] = pk.u;
    }
  }
}

// ---------------- K2: R19 flash (dbuf + atomic-append compaction + defer-max
//                  + ones-MFMA lsum + fused out-proj), unchanged ----------
__global__ __launch_bounds__(256) void flash_kernel(
    const f16* __restrict__ qp, const f16* __restrict__ kp, const f16* __restrict__ vpT,
    const f16* __restrict__ WoT, const float* __restrict__ bo, float* __restrict__ out)
{
  __shared__ __align__(16) f16 Klds[2][64][72];  // dbuf; [0] reused for O in epilogue
  __shared__ __align__(16) f16 Vlds[2][64][72];
  __shared__ __align__(16) f16 Plds[4][16][72];  // per-wave P (A-frag layout)
  __shared__ unsigned short Idl[4][1024];        // per-wave survivor id list
  __shared__ uint32_t Cnt[4];                    // per-wave survivor count
  const int tid = threadIdx.x;
  const int lane = tid & 63, wave = tid >> 6;
  const int llo = lane & 15, lhi = lane >> 4;
  const int bh = blockIdx.y;
  const int q0 = blockIdx.x * 64;

  const f16* qbase = qp + ((long)bh*2048 + q0 + wave*16 + llo)*64 + lhi*8;
  f16x8 qf0 = *(const f16x8*)qbase;
  f16x8 qf1 = *(const f16x8*)(qbase + 32);

  f16x8 ones1;
  #pragma unroll
  for (int e=0;e<8;e++) ones1[e] = (f16)1.0f;

  f32x4 O[4];
  float mrun[4], lrun[4];
  #pragma unroll
  for (int n=0;n<4;n++){ O[n][0]=0.f;O[n][1]=0.f;O[n][2]=0.f;O[n][3]=0.f; }
  #pragma unroll
  for (int j=0;j<4;j++){ mrun[j] = -__builtin_inff(); lrun[j]=0.f; }

  const int sr = tid >> 2;            // stage row 0..63
  const int sc = (tid & 3) * 16;      // stage col (f16)
  const f16* ksrc = kp + (long)bh*2048*64 + (long)sr*64 + sc;    // +4096/tile
  const f16* vsrc = vpT + (long)bh*64*2048 + (long)sr*2048 + sc; // +64/tile
  uint32_t base_w = (uint32_t)((bh*2048 + q0 + wave*16)*2048);

  // preload tile 0 into regs, stage to buffer 0
  f16x8 kr0 = *(const f16x8*)(ksrc);
  f16x8 kr1 = *(const f16x8*)(ksrc + 8);
  f16x8 vr0 = *(const f16x8*)(vsrc);
  f16x8 vr1 = *(const f16x8*)(vsrc + 8);
  *(f16x8*)&Klds[0][sr][sc]   = kr0;
  *(f16x8*)&Klds[0][sr][sc+8] = kr1;
  *(f16x8*)&Vlds[0][sr][sc]   = vr0;
  *(f16x8*)&Vlds[0][sr][sc+8] = vr1;
  __syncthreads();

  for (int t = 0; t < 32; ++t, base_w += 64u){
    const int buf = t & 1;
    // issue next tile's loads (complete during this tile's compute)
    if (t < 31){
      const f16* ks = ksrc + (long)(t+1)*4096;
      kr0 = *(const f16x8*)ks;
      kr1 = *(const f16x8*)(ks + 8);
      const f16* vs = vsrc + (long)(t+1)*64;
      vr0 = *(const f16x8*)vs;
      vr1 = *(const f16x8*)(vs + 8);
    }

    f32x4 s[4];
    #pragma unroll
    for (int n=0;n<4;n++){ s[n][0]=0.f;s[n][1]=0.f;s[n][2]=0.f;s[n][3]=0.f; }
    #pragma unroll
    for (int n=0;n<4;n++){
      f16x8 kf0 = *(const f16x8*)&Klds[buf][16*n+llo][lhi*8];
      s[n] = __builtin_amdgcn_mfma_f32_16x16x32_f16(qf0, kf0, s[n], 0,0,0);
      f16x8 kf1 = *(const f16x8*)&Klds[buf][16*n+llo][32+lhi*8];
      s[n] = __builtin_amdgcn_mfma_f32_16x16x32_f16(qf1, kf1, s[n], 0,0,0);
    }
    float pmax[4];
    #pragma unroll
    for (int j=0;j<4;j++)
      pmax[j] = fmaxf(fmaxf(s[0][j],s[1][j]), fmaxf(s[2][j],s[3][j]));
    #pragma unroll
    for (int off=1; off<16; off<<=1){
      #pragma unroll
      for (int j=0;j<4;j++) pmax[j] = fmaxf(pmax[j], __shfl_xor(pmax[j], off));
    }

    // defer-max (THR=8): only rescale when a row's max advances by >8.
    float adv = fmaxf(fmaxf(pmax[0]-mrun[0], pmax[1]-mrun[1]),
                      fmaxf(pmax[2]-mrun[2], pmax[3]-mrun[3]));
    if (adv > 8.0f){
      float esc[4];
      #pragma unroll
      for (int j=0;j<4;j++){
        float mnew = fmaxf(mrun[j], pmax[j]);
        esc[j] = __expf(mrun[j] - mnew);
        mrun[j] = mnew;
      }
      #pragma unroll
      for (int j=0;j<4;j++) lrun[j] *= esc[j];
      #pragma unroll
      for (int n=0;n<4;n++)
        #pragma unroll
        for (int j=0;j<4;j++) O[n][j] *= esc[j];
    }

    float p[4][4];
    #pragma unroll
    for (int n=0;n<4;n++)
      #pragma unroll
      for (int j=0;j<4;j++)
        p[n][j] = __expf(s[n][j] - mrun[j]);

    // ---- store P (pre-dropout, scaled 1/0.9); survivors -> atomic append ----
    if (lane == 0) Cnt[wave] = 0;
    #pragma unroll
    for (int j=0;j<4;j++){
      #pragma unroll
      for (int n=0;n<4;n++){
        float pm = p[n][j]*(1.0f/0.9f);
        Plds[wave][lhi*4+j][16*n+llo] = (f16)pm;
        if (pm > 0x1.0p-25f){                    // (f16)pm != 0
          uint32_t pos = atomicAdd(&Cnt[wave], 1u);
          Idl[wave][pos] = (unsigned short)((j<<8)|(n<<6)|lane);
        }
      }
    }
    uint32_t cnt = Cnt[wave];

    // ---- lsum via ones-MFMA on pre-scatter P (rowsum); lsum = 0.9 * Σ pm ----
    {
      f16x8 la0 = *(const f16x8*)&Plds[wave][llo][lhi*8];
      f16x8 la1 = *(const f16x8*)&Plds[wave][llo][32+lhi*8];
      f32x4 lc; lc[0]=0.f; lc[1]=0.f; lc[2]=0.f; lc[3]=0.f;
      lc = __builtin_amdgcn_mfma_f32_16x16x32_f16(la0, ones1, lc, 0,0,0);
      lc = __builtin_amdgcn_mfma_f32_16x16x32_f16(la1, ones1, lc, 0,0,0);
      #pragma unroll
      for (int j=0;j<4;j++) lrun[j] += 0.9f*lc[j];
    }

    // ---- threefry only for survivors; drops scatter zeros into Plds ----
    for (uint32_t pb = 0; pb < cnt; pb += 64){
      uint32_t idx = pb + (uint32_t)lane;
      if (idx < cnt){
        uint32_t id = (uint32_t)Idl[wave][idx];
        uint32_t jj = (id>>8)&3u, nn = (id>>6)&3u, ln = id & 63u;
        uint32_t i = base_w + (ln>>4)*8192u + jj*2048u + nn*16u + (ln&15u);
        uint32_t bits = tf_bits(i);
        if (bits >= 0xE6666600u)                 // uniform(bits) >= 0.9 -> drop
          Plds[wave][(ln>>4)*4+jj][16*nn+(ln&15u)] = (f16)0;
      }
    }

    f16x8 pa0 = *(const f16x8*)&Plds[wave][llo][lhi*8];
    f16x8 pa1 = *(const f16x8*)&Plds[wave][llo][32+lhi*8];
    #pragma unroll
    for (int n=0;n<4;n++){
      f16x8 vf0 = *(const f16x8*)&Vlds[buf][16*n+llo][lhi*8];
      O[n] = __builtin_amdgcn_mfma_f32_16x16x32_f16(pa0, vf0, O[n], 0,0,0);
      f16x8 vf1 = *(const f16x8*)&Vlds[buf][16*n+llo][32+lhi*8];
      O[n] = __builtin_amdgcn_mfma_f32_16x16x32_f16(pa1, vf1, O[n], 0,0,0);
    }

    // stage next tile into the other buffer; ONE barrier per iteration
    if (t < 31){
      *(f16x8*)&Klds[buf^1][sr][sc]   = kr0;
      *(f16x8*)&Klds[buf^1][sr][sc+8] = kr1;
      *(f16x8*)&Vlds[buf^1][sr][sc]   = vr0;
      *(f16x8*)&Vlds[buf^1][sr][sc+8] = vr1;
    }
    __syncthreads();
  }

  // ---- fused epilogue: out[rows] = (O/l) @ Wo + bo, O staged f16 in Klds[0] ----
  float rl[4];
  #pragma unroll
  for (int j=0;j<4;j++) rl[j] = 1.0f / lrun[j];
  #pragma unroll
  for (int n=0;n<4;n++)
    #pragma unroll
    for (int j=0;j<4;j++)
      Klds[0][wave*16 + lhi*4 + j][16*n + llo] = (f16)(O[n][j]*rl[j]);
  __syncthreads();

  f16x8 af0 = *(const f16x8*)&Klds[0][wave*16 + llo][lhi*8];
  f16x8 af1 = *(const f16x8*)&Klds[0][wave*16 + llo][32 + lhi*8];
  const long robase = (long)bh*2048 + q0 + wave*16 + lhi*4;
  for (int n0 = 0; n0 < 1024; n0 += 16){
    f16x8 b0 = *(const f16x8*)&WoT[(long)(n0+llo)*64 + lhi*8];
    f16x8 b1 = *(const f16x8*)&WoT[(long)(n0+llo)*64 + 32 + lhi*8];
    float bb = bo[n0+llo];
    f32x4 c; c[0]=bb; c[1]=bb; c[2]=bb; c[3]=bb;
    c = __builtin_amdgcn_mfma_f32_16x16x32_f16(af0, b0, c, 0,0,0);
    c = __builtin_amdgcn_mfma_f32_16x16x32_f16(af1, b1, c, 0,0,0);
    #pragma unroll
    for (int j=0;j<4;j++)
      out[(robase + j)*1024 + n0 + llo] = c[j];
  }
}

extern "C" void kernel_launch(void* const* d_in, const int* in_sizes, int n_in,
                              void* d_out, int out_size, void* d_ws, size_t ws_size,
                              hipStream_t stream){
  const float* query = (const float*)d_in[0];
  const float* key   = (const float*)d_in[1];
  const float* value = (const float*)d_in[2];
  const float* Wq = (const float*)d_in[3];
  const float* bq = (const float*)d_in[4];
  const float* Wk = (const float*)d_in[5];
  const float* bk = (const float*)d_in[6];
  const float* Wv = (const float*)d_in[7];
  const float* bv = (const float*)d_in[8];
  const float* Wo = (const float*)d_in[9];
  const float* bo = (const float*)d_in[10];
  float* out = (float*)d_out;

  char* ws = (char*)d_ws;
  f16* qp   = (f16*)(ws);                               // 4 MiB
  f16* kp   = (f16*)(ws + ((size_t)4<<20));             // 4 MiB
  f16* vpT  = (f16*)(ws + ((size_t)8<<20));             // 4 MiB
  f16* WoT  = (f16*)(ws + ((size_t)20<<20));            // 128 KiB

  proj_kernel<0><<<dim3(1024), dim3(256), 0, stream>>>(
      query,key,value,Wq,bq,Wk,bk,Wv,bv,Wo,qp,kp,vpT,WoT);
  proj_kernel<1><<<dim3(768), dim3(256), 0, stream>>>(
      query,key,value,Wq,bq,Wk,bk,Wv,bv,Wo,qp,kp,vpT,WoT);
  flash_kernel<<<dim3(32,16), dim3(256), 0, stream>>>(qp,kp,vpT,WoT,bo,out);
}

// Round 21
// 240.085 us; speedup vs baseline: 1.0630x; 1.0630x over previous
//
#include <hip/hip_runtime.h>
#include <stdint.h>

typedef _Float16 f16;
typedef __attribute__((ext_vector_type(8))) _Float16 f16x8;
typedef __attribute__((ext_vector_type(4))) float f32x4;

// ---------------- threefry2x32 (JAX partitionable, key=(0,42), counts=(0,i)) ----
__device__ __forceinline__ uint32_t rotl1(uint32_t x, uint32_t n){
  return __builtin_amdgcn_alignbit(x, x, 32u - n);
}
__device__ __forceinline__ uint32_t tf_bits(uint32_t i){
  const uint32_t ks1 = 42u, ks2 = 0x1BD11BDAu ^ 42u;
  uint32_t x0 = 0u, x1 = i + 42u;
#define R4(a,b,c,d) \
  x0 += x1; x1 = rotl1(x1,a); x1 ^= x0; \
  x0 += x1; x1 = rotl1(x1,b); x1 ^= x0; \
  x0 += x1; x1 = rotl1(x1,c); x1 ^= x0; \
  x0 += x1; x1 = rotl1(x1,d); x1 ^= x0;
  R4(13,15,26,6)  x0 += ks1; x1 += ks2 + 1u;
  R4(17,29,16,24) x0 += ks2; x1 += 2u;         // ks0 = 0
  R4(13,15,26,6)               x1 += ks1 + 3u; // x0 += ks0 = +0
  R4(17,29,16,24) x0 += ks1; x1 += ks2 + 4u;
  R4(13,15,26,6)  x0 += ks2; x1 += 5u;         // ks0 = 0
#undef R4
  return x0 ^ x1;
}

// ---------------- K1 (A/B template): R4-exact projections, SPLIT PAIR --------
template<int PACKED>
__global__ __launch_bounds__(256) void proj_kernel(
    const float* __restrict__ query, const float* __restrict__ keyp, const float* __restrict__ value,
    const float* __restrict__ Wq, const float* __restrict__ bq,
    const float* __restrict__ Wk, const float* __restrict__ bk,
    const float* __restrict__ Wv, const float* __restrict__ bv,
    const float* __restrict__ Wo,
    f16* __restrict__ qp, f16* __restrict__ kp, f16* __restrict__ vpT,
    f16* __restrict__ WoT)
{
  __shared__ __align__(16) f16 Alds[64][40];   // rows x k (80B stride)
  __shared__ __align__(16) f16 Wlds[64][40];   // [col][k]
  const int bid = blockIdx.x;
  const int tid = threadIdx.x;
  const int lane = tid & 63, wave = tid >> 6;
  const int llo = lane & 15, lhi = lane >> 4;

  int p;
  if (PACKED == 0){
    if (bid < 256){
      int t = bid*256 + tid;
      int n = t & 1023, k = t >> 10;
      WoT[(long)n*64 + k] = (f16)Wo[(long)k*1024 + n];
      return;
    }
    p = bid - 256;            // [0,768)
  } else {
    p = 768 + bid;            // [768,1536)
  }

  const int which = p >> 9;           // 0..2
  const long m0 = (long)(p & 511) * 64;
  const float* A    = which==0 ? query : (which==1 ? keyp : value);
  const float* W    = which==0 ? Wq    : (which==1 ? Wk   : Wv);
  const float* bias = which==0 ? bq    : (which==1 ? bk   : bv);

  f32x4 acc[4];
  #pragma unroll
  for (int n=0;n<4;n++){
    float bb = bias[16*n + llo];
    acc[n][0]=bb; acc[n][1]=bb; acc[n][2]=bb; acc[n][3]=bb;
  }

  const int ar = tid >> 2;            // 0..63
  const int ac = (tid & 3) * 8;
  const int wcol = tid & 63;
  const int wk = (tid >> 6) * 8;

  for (int k0 = 0; k0 < 1024; k0 += 32){
    {
      const float* asrc = A + (m0 + ar)*1024 + k0 + ac;
      float4 v0 = *(const float4*)asrc;
      float4 v1 = *(const float4*)(asrc + 4);
      if (PACKED == 0){
        f16* ad = &Alds[ar][ac];
        ad[0]=(f16)v0.x; ad[1]=(f16)v0.y; ad[2]=(f16)v0.z; ad[3]=(f16)v0.w;
        ad[4]=(f16)v1.x; ad[5]=(f16)v1.y; ad[6]=(f16)v1.z; ad[7]=(f16)v1.w;
      } else {
        union { f16 h[8]; f16x8 v; } aw;
        aw.h[0]=(f16)v0.x; aw.h[1]=(f16)v0.y; aw.h[2]=(f16)v0.z; aw.h[3]=(f16)v0.w;
        aw.h[4]=(f16)v1.x; aw.h[5]=(f16)v1.y; aw.h[6]=(f16)v1.z; aw.h[7]=(f16)v1.w;
        *(f16x8*)&Alds[ar][ac] = aw.v;
      }
      f16 wt[8];
      #pragma unroll
      for (int j=0;j<8;j++) wt[j] = (f16)W[(long)(k0+wk+j)*64 + wcol];
      *(f16x8*)&Wlds[wcol][wk] = *(f16x8*)wt;
    }
    __syncthreads();
    f16x8 af = *(const f16x8*)&Alds[wave*16 + llo][lhi*8];
    #pragma unroll
    for (int n=0;n<4;n++){
      f16x8 bf = *(const f16x8*)&Wlds[16*n + llo][lhi*8];
      acc[n] = __builtin_amdgcn_mfma_f32_16x16x32_f16(af, bf, acc[n], 0,0,0);
    }
    __syncthreads();
  }

  if (which < 2){
    const float scale = (which==0) ? 2.0f : 1.0f;   // fold dk=2.0 into q
    f16* dst = (which==0) ? qp : kp;
    #pragma unroll
    for (int n=0;n<4;n++)
      #pragma unroll
      for (int j=0;j<4;j++){
        long row = m0 + wave*16 + lhi*4 + j;
        dst[row*64 + 16*n + llo] = (f16)(acc[n][j]*scale);
      }
  } else {
    long row0 = m0 + wave*16 + lhi*4;
    long bh = row0 >> 11;
    long lr = row0 & 2047;
    #pragma unroll
    for (int n=0;n<4;n++){
      union { f16 h[4]; ushort4 u; } pk;
      #pragma unroll
      for (int j=0;j<4;j++) pk.h[j] = (f16)acc[n][j];
      *(ushort4*)&vpT[(bh*64 + 16*n + llo)*2048 + lr] = pk.u;
    }
  }
}

// ---------------- K2: R18 flash (dbuf + ballot compaction + ones-MFMA lsum)
//                  + defer-max ONLY (single-variable change vs R18) ----------
__global__ __launch_bounds__(256) void flash_kernel(
    const f16* __restrict__ qp, const f16* __restrict__ kp, const f16* __restrict__ vpT,
    const f16* __restrict__ WoT, const float* __restrict__ bo, float* __restrict__ out)
{
  __shared__ __align__(16) f16 Klds[2][64][72];  // dbuf; [0] reused for O in epilogue
  __shared__ __align__(16) f16 Vlds[2][64][72];
  __shared__ __align__(16) f16 Plds[4][16][72];  // per-wave P (A-frag layout)
  __shared__ unsigned short Idl[4][1024];        // per-wave survivor id list
  const int tid = threadIdx.x;
  const int lane = tid & 63, wave = tid >> 6;
  const int llo = lane & 15, lhi = lane >> 4;
  const int bh = blockIdx.y;
  const int q0 = blockIdx.x * 64;

  const f16* qbase = qp + ((long)bh*2048 + q0 + wave*16 + llo)*64 + lhi*8;
  f16x8 qf0 = *(const f16x8*)qbase;
  f16x8 qf1 = *(const f16x8*)(qbase + 32);

  f16x8 ones1;
  #pragma unroll
  for (int e=0;e<8;e++) ones1[e] = (f16)1.0f;

  f32x4 O[4];
  float mrun[4], lrun[4];
  #pragma unroll
  for (int n=0;n<4;n++){ O[n][0]=0.f;O[n][1]=0.f;O[n][2]=0.f;O[n][3]=0.f; }
  #pragma unroll
  for (int j=0;j<4;j++){ mrun[j] = -__builtin_inff(); lrun[j]=0.f; }

  const int sr = tid >> 2;            // stage row 0..63
  const int sc = (tid & 3) * 16;      // stage col (f16)
  const f16* ksrc = kp + (long)bh*2048*64 + (long)sr*64 + sc;    // +4096/tile
  const f16* vsrc = vpT + (long)bh*64*2048 + (long)sr*2048 + sc; // +64/tile
  uint32_t base_w = (uint32_t)((bh*2048 + q0 + wave*16)*2048);

  // preload tile 0 into regs, stage to buffer 0
  f16x8 kr0 = *(const f16x8*)(ksrc);
  f16x8 kr1 = *(const f16x8*)(ksrc + 8);
  f16x8 vr0 = *(const f16x8*)(vsrc);
  f16x8 vr1 = *(const f16x8*)(vsrc + 8);
  *(f16x8*)&Klds[0][sr][sc]   = kr0;
  *(f16x8*)&Klds[0][sr][sc+8] = kr1;
  *(f16x8*)&Vlds[0][sr][sc]   = vr0;
  *(f16x8*)&Vlds[0][sr][sc+8] = vr1;
  __syncthreads();

  for (int t = 0; t < 32; ++t, base_w += 64u){
    const int buf = t & 1;
    // issue next tile's loads (complete during this tile's compute)
    if (t < 31){
      const f16* ks = ksrc + (long)(t+1)*4096;
      kr0 = *(const f16x8*)ks;
      kr1 = *(const f16x8*)(ks + 8);
      const f16* vs = vsrc + (long)(t+1)*64;
      vr0 = *(const f16x8*)vs;
      vr1 = *(const f16x8*)(vs + 8);
    }

    f32x4 s[4];
    #pragma unroll
    for (int n=0;n<4;n++){ s[n][0]=0.f;s[n][1]=0.f;s[n][2]=0.f;s[n][3]=0.f; }
    #pragma unroll
    for (int n=0;n<4;n++){
      f16x8 kf0 = *(const f16x8*)&Klds[buf][16*n+llo][lhi*8];
      s[n] = __builtin_amdgcn_mfma_f32_16x16x32_f16(qf0, kf0, s[n], 0,0,0);
      f16x8 kf1 = *(const f16x8*)&Klds[buf][16*n+llo][32+lhi*8];
      s[n] = __builtin_amdgcn_mfma_f32_16x16x32_f16(qf1, kf1, s[n], 0,0,0);
    }
    float pmax[4];
    #pragma unroll
    for (int j=0;j<4;j++)
      pmax[j] = fmaxf(fmaxf(s[0][j],s[1][j]), fmaxf(s[2][j],s[3][j]));
    #pragma unroll
    for (int off=1; off<16; off<<=1){
      #pragma unroll
      for (int j=0;j<4;j++) pmax[j] = fmaxf(pmax[j], __shfl_xor(pmax[j], off));
    }

    // defer-max (THR=8): only rescale when a row's max advances by >8.
    // P then bounded by e^8/0.9 (f16-safe); skips esc/exp/O-mul most tiles.
    float adv = fmaxf(fmaxf(pmax[0]-mrun[0], pmax[1]-mrun[1]),
                      fmaxf(pmax[2]-mrun[2], pmax[3]-mrun[3]));
    if (adv > 8.0f){
      float esc[4];
      #pragma unroll
      for (int j=0;j<4;j++){
        float mnew = fmaxf(mrun[j], pmax[j]);
        esc[j] = __expf(mrun[j] - mnew);
        mrun[j] = mnew;
      }
      #pragma unroll
      for (int j=0;j<4;j++) lrun[j] *= esc[j];
      #pragma unroll
      for (int n=0;n<4;n++)
        #pragma unroll
        for (int j=0;j<4;j++) O[n][j] *= esc[j];
    }

    float p[4][4];
    #pragma unroll
    for (int n=0;n<4;n++)
      #pragma unroll
      for (int j=0;j<4;j++)
        p[n][j] = __expf(s[n][j] - mrun[j]);

    // ---- store P (pre-dropout, scaled 1/0.9) + ballot survivor compaction ----
    uint32_t cnt = 0;
    #pragma unroll
    for (int j=0;j<4;j++){
      #pragma unroll
      for (int n=0;n<4;n++){
        float pm = p[n][j]*(1.0f/0.9f);
        bool surv = pm > 0x1.0p-25f;            // (f16)pm != 0
        Plds[wave][lhi*4+j][16*n+llo] = (f16)pm;
        unsigned long long mk = __ballot(surv);
        if (mk){
          uint32_t pre = __builtin_amdgcn_mbcnt_hi((uint32_t)(mk>>32),
                         __builtin_amdgcn_mbcnt_lo((uint32_t)mk, 0u));
          if (surv)
            Idl[wave][cnt + pre] = (unsigned short)((j<<8)|(n<<6)|lane);
          cnt += (uint32_t)__builtin_popcountll(mk);
        }
      }
    }

    // ---- lsum via ones-MFMA on pre-scatter P (rowsum); lsum = 0.9 * Σ pm ----
    {
      f16x8 la0 = *(const f16x8*)&Plds[wave][llo][lhi*8];
      f16x8 la1 = *(const f16x8*)&Plds[wave][llo][32+lhi*8];
      f32x4 lc; lc[0]=0.f; lc[1]=0.f; lc[2]=0.f; lc[3]=0.f;
      lc = __builtin_amdgcn_mfma_f32_16x16x32_f16(la0, ones1, lc, 0,0,0);
      lc = __builtin_amdgcn_mfma_f32_16x16x32_f16(la1, ones1, lc, 0,0,0);
      #pragma unroll
      for (int j=0;j<4;j++) lrun[j] += 0.9f*lc[j];
    }

    // ---- threefry only for survivors; drops scatter zeros into Plds ----
    for (uint32_t pb = 0; pb < cnt; pb += 64){
      uint32_t idx = pb + (uint32_t)lane;
      if (idx < cnt){
        uint32_t id = (uint32_t)Idl[wave][idx];
        uint32_t jj = (id>>8)&3u, nn = (id>>6)&3u, ln = id & 63u;
        uint32_t i = base_w + (ln>>4)*8192u + jj*2048u + nn*16u + (ln&15u);
        uint32_t bits = tf_bits(i);
        if (bits >= 0xE6666600u)                 // uniform(bits) >= 0.9 -> drop
          Plds[wave][(ln>>4)*4+jj][16*nn+(ln&15u)] = (f16)0;
      }
    }

    f16x8 pa0 = *(const f16x8*)&Plds[wave][llo][lhi*8];
    f16x8 pa1 = *(const f16x8*)&Plds[wave][llo][32+lhi*8];
    #pragma unroll
    for (int n=0;n<4;n++){
      f16x8 vf0 = *(const f16x8*)&Vlds[buf][16*n+llo][lhi*8];
      O[n] = __builtin_amdgcn_mfma_f32_16x16x32_f16(pa0, vf0, O[n], 0,0,0);
      f16x8 vf1 = *(const f16x8*)&Vlds[buf][16*n+llo][32+lhi*8];
      O[n] = __builtin_amdgcn_mfma_f32_16x16x32_f16(pa1, vf1, O[n], 0,0,0);
    }

    // stage next tile into the other buffer; ONE barrier per iteration
    if (t < 31){
      *(f16x8*)&Klds[buf^1][sr][sc]   = kr0;
      *(f16x8*)&Klds[buf^1][sr][sc+8] = kr1;
      *(f16x8*)&Vlds[buf^1][sr][sc]   = vr0;
      *(f16x8*)&Vlds[buf^1][sr][sc+8] = vr1;
    }
    __syncthreads();
  }

  // ---- fused epilogue: out[rows] = (O/l) @ Wo + bo, O staged f16 in Klds[0] ----
  float rl[4];
  #pragma unroll
  for (int j=0;j<4;j++) rl[j] = 1.0f / lrun[j];
  #pragma unroll
  for (int n=0;n<4;n++)
    #pragma unroll
    for (int j=0;j<4;j++)
      Klds[0][wave*16 + lhi*4 + j][16*n + llo] = (f16)(O[n][j]*rl[j]);
  __syncthreads();

  f16x8 af0 = *(const f16x8*)&Klds[0][wave*16 + llo][lhi*8];
  f16x8 af1 = *(const f16x8*)&Klds[0][wave*16 + llo][32 + lhi*8];
  const long robase = (long)bh*2048 + q0 + wave*16 + lhi*4;
  for (int n0 = 0; n0 < 1024; n0 += 16){
    f16x8 b0 = *(const f16x8*)&WoT[(long)(n0+llo)*64 + lhi*8];
    f16x8 b1 = *(const f16x8*)&WoT[(long)(n0+llo)*64 + 32 + lhi*8];
    float bb = bo[n0+llo];
    f32x4 c; c[0]=bb; c[1]=bb; c[2]=bb; c[3]=bb;
    c = __builtin_amdgcn_mfma_f32_16x16x32_f16(af0, b0, c, 0,0,0);
    c = __builtin_amdgcn_mfma_f32_16x16x32_f16(af1, b1, c, 0,0,0);
    #pragma unroll
    for (int j=0;j<4;j++)
      out[(robase + j)*1024 + n0 + llo] = c[j];
  }
}

extern "C" void kernel_launch(void* const* d_in, const int* in_sizes, int n_in,
                              void* d_out, int out_size, void* d_ws, size_t ws_size,
                              hipStream_t stream){
  const float* query = (const float*)d_in[0];
  const float* key   = (const float*)d_in[1];
  const float* value = (const float*)d_in[2];
  const float* Wq = (const float*)d_in[3];
  const float* bq = (const float*)d_in[4];
  const float* Wk = (const float*)d_in[5];
  const float* bk = (const float*)d_in[6];
  const float* Wv = (const float*)d_in[7];
  const float* bv = (const float*)d_in[8];
  const float* Wo = (const float*)d_in[9];
  const float* bo = (const float*)d_in[10];
  float* out = (float*)d_out;

  char* ws = (char*)d_ws;
  f16* qp   = (f16*)(ws);                               // 4 MiB
  f16* kp   = (f16*)(ws + ((size_t)4<<20));             // 4 MiB
  f16* vpT  = (f16*)(ws + ((size_t)8<<20));             // 4 MiB
  f16* WoT  = (f16*)(ws + ((size_t)20<<20));            // 128 KiB

  proj_kernel<0><<<dim3(1024), dim3(256), 0, stream>>>(
      query,key,value,Wq,bq,Wk,bk,Wv,bv,Wo,qp,kp,vpT,WoT);
  proj_kernel<1><<<dim3(768), dim3(256), 0, stream>>>(
      query,key,value,Wq,bq,Wk,bk,Wv,bv,Wo,qp,kp,vpT,WoT);
  flash_kernel<<<dim3(32,16), dim3(256), 0, stream>>>(qp,kp,vpT,WoT,bo,out);
}

// Round 22
// 231.933 us; speedup vs baseline: 1.1004x; 1.0351x over previous
//
#include <hip/hip_runtime.h>
#include <stdint.h>

typedef _Float16 f16;
typedef __attribute__((ext_vector_type(8))) _Float16 f16x8;
typedef __attribute__((ext_vector_type(4))) float f32x4;

// ---------------- threefry2x32 (JAX partitionable, key=(0,42), counts=(0,i)) ----
__device__ __forceinline__ uint32_t rotl1(uint32_t x, uint32_t n){
  return __builtin_amdgcn_alignbit(x, x, 32u - n);
}
__device__ __forceinline__ uint32_t tf_bits(uint32_t i){
  const uint32_t ks1 = 42u, ks2 = 0x1BD11BDAu ^ 42u;
  uint32_t x0 = 0u, x1 = i + 42u;
#define R4(a,b,c,d) \
  x0 += x1; x1 = rotl1(x1,a); x1 ^= x0; \
  x0 += x1; x1 = rotl1(x1,b); x1 ^= x0; \
  x0 += x1; x1 = rotl1(x1,c); x1 ^= x0; \
  x0 += x1; x1 = rotl1(x1,d); x1 ^= x0;
  R4(13,15,26,6)  x0 += ks1; x1 += ks2 + 1u;
  R4(17,29,16,24) x0 += ks2; x1 += 2u;         // ks0 = 0
  R4(13,15,26,6)               x1 += ks1 + 3u; // x0 += ks0 = +0
  R4(17,29,16,24) x0 += ks1; x1 += ks2 + 4u;
  R4(13,15,26,6)  x0 += ks2; x1 += 5u;         // ks0 = 0
#undef R4
  return x0 ^ x1;
}

// ---------------- K1 (A/B template): R4-exact projections, SPLIT PAIR --------
template<int PACKED>
__global__ __launch_bounds__(256) void proj_kernel(
    const float* __restrict__ query, const float* __restrict__ keyp, const float* __restrict__ value,
    const float* __restrict__ Wq, const float* __restrict__ bq,
    const float* __restrict__ Wk, const float* __restrict__ bk,
    const float* __restrict__ Wv, const float* __restrict__ bv,
    const float* __restrict__ Wo,
    f16* __restrict__ qp, f16* __restrict__ kp, f16* __restrict__ vpT,
    f16* __restrict__ WoT)
{
  __shared__ __align__(16) f16 Alds[64][40];   // rows x k (80B stride)
  __shared__ __align__(16) f16 Wlds[64][40];   // [col][k]
  const int bid = blockIdx.x;
  const int tid = threadIdx.x;
  const int lane = tid & 63, wave = tid >> 6;
  const int llo = lane & 15, lhi = lane >> 4;

  int p;
  if (PACKED == 0){
    if (bid < 256){
      int t = bid*256 + tid;
      int n = t & 1023, k = t >> 10;
      WoT[(long)n*64 + k] = (f16)Wo[(long)k*1024 + n];
      return;
    }
    p = bid - 256;            // [0,768)
  } else {
    p = 768 + bid;            // [768,1536)
  }

  const int which = p >> 9;           // 0..2
  const long m0 = (long)(p & 511) * 64;
  const float* A    = which==0 ? query : (which==1 ? keyp : value);
  const float* W    = which==0 ? Wq    : (which==1 ? Wk   : Wv);
  const float* bias = which==0 ? bq    : (which==1 ? bk   : bv);

  f32x4 acc[4];
  #pragma unroll
  for (int n=0;n<4;n++){
    float bb = bias[16*n + llo];
    acc[n][0]=bb; acc[n][1]=bb; acc[n][2]=bb; acc[n][3]=bb;
  }

  const int ar = tid >> 2;            // 0..63
  const int ac = (tid & 3) * 8;
  const int wcol = tid & 63;
  const int wk = (tid >> 6) * 8;

  for (int k0 = 0; k0 < 1024; k0 += 32){
    {
      const float* asrc = A + (m0 + ar)*1024 + k0 + ac;
      float4 v0 = *(const float4*)asrc;
      float4 v1 = *(const float4*)(asrc + 4);
      if (PACKED == 0){
        f16* ad = &Alds[ar][ac];
        ad[0]=(f16)v0.x; ad[1]=(f16)v0.y; ad[2]=(f16)v0.z; ad[3]=(f16)v0.w;
        ad[4]=(f16)v1.x; ad[5]=(f16)v1.y; ad[6]=(f16)v1.z; ad[7]=(f16)v1.w;
      } else {
        union { f16 h[8]; f16x8 v; } aw;
        aw.h[0]=(f16)v0.x; aw.h[1]=(f16)v0.y; aw.h[2]=(f16)v0.z; aw.h[3]=(f16)v0.w;
        aw.h[4]=(f16)v1.x; aw.h[5]=(f16)v1.y; aw.h[6]=(f16)v1.z; aw.h[7]=(f16)v1.w;
        *(f16x8*)&Alds[ar][ac] = aw.v;
      }
      f16 wt[8];
      #pragma unroll
      for (int j=0;j<8;j++) wt[j] = (f16)W[(long)(k0+wk+j)*64 + wcol];
      *(f16x8*)&Wlds[wcol][wk] = *(f16x8*)wt;
    }
    __syncthreads();
    f16x8 af = *(const f16x8*)&Alds[wave*16 + llo][lhi*8];
    #pragma unroll
    for (int n=0;n<4;n++){
      f16x8 bf = *(const f16x8*)&Wlds[16*n + llo][lhi*8];
      acc[n] = __builtin_amdgcn_mfma_f32_16x16x32_f16(af, bf, acc[n], 0,0,0);
    }
    __syncthreads();
  }

  if (which < 2){
    const float scale = (which==0) ? 2.0f : 1.0f;   // fold dk=2.0 into q
    f16* dst = (which==0) ? qp : kp;
    #pragma unroll
    for (int n=0;n<4;n++)
      #pragma unroll
      for (int j=0;j<4;j++){
        long row = m0 + wave*16 + lhi*4 + j;
        dst[row*64 + 16*n + llo] = (f16)(acc[n][j]*scale);
      }
  } else {
    long row0 = m0 + wave*16 + lhi*4;
    long bh = row0 >> 11;
    long lr = row0 & 2047;
    #pragma unroll
    for (int n=0;n<4;n++){
      union { f16 h[4]; ushort4 u; } pk;
      #pragma unroll
      for (int j=0;j<4;j++) pk.h[j] = (f16)acc[n][j];
      *(ushort4*)&vpT[(bh*64 + 16*n + llo)*2048 + lr] = pk.u;
    }
  }
}

// ---------------- K2: R18-exact flash (dbuf + ballot compaction + ones-MFMA
//                  lsum + fused out-proj) + T5 s_setprio around MFMA clusters --
__global__ __launch_bounds__(256) void flash_kernel(
    const f16* __restrict__ qp, const f16* __restrict__ kp, const f16* __restrict__ vpT,
    const f16* __restrict__ WoT, const float* __restrict__ bo, float* __restrict__ out)
{
  __shared__ __align__(16) f16 Klds[2][64][72];  // dbuf; [0] reused for O in epilogue
  __shared__ __align__(16) f16 Vlds[2][64][72];
  __shared__ __align__(16) f16 Plds[4][16][72];  // per-wave P (A-frag layout)
  __shared__ unsigned short Idl[4][1024];        // per-wave survivor id list
  const int tid = threadIdx.x;
  const int lane = tid & 63, wave = tid >> 6;
  const int llo = lane & 15, lhi = lane >> 4;
  const int bh = blockIdx.y;
  const int q0 = blockIdx.x * 64;

  const f16* qbase = qp + ((long)bh*2048 + q0 + wave*16 + llo)*64 + lhi*8;
  f16x8 qf0 = *(const f16x8*)qbase;
  f16x8 qf1 = *(const f16x8*)(qbase + 32);

  f16x8 ones1;
  #pragma unroll
  for (int e=0;e<8;e++) ones1[e] = (f16)1.0f;

  f32x4 O[4];
  float mrun[4], lrun[4];
  #pragma unroll
  for (int n=0;n<4;n++){ O[n][0]=0.f;O[n][1]=0.f;O[n][2]=0.f;O[n][3]=0.f; }
  #pragma unroll
  for (int j=0;j<4;j++){ mrun[j] = -__builtin_inff(); lrun[j]=0.f; }

  const int sr = tid >> 2;            // stage row 0..63
  const int sc = (tid & 3) * 16;      // stage col (f16)
  const f16* ksrc = kp + (long)bh*2048*64 + (long)sr*64 + sc;    // +4096/tile
  const f16* vsrc = vpT + (long)bh*64*2048 + (long)sr*2048 + sc; // +64/tile
  uint32_t base_w = (uint32_t)((bh*2048 + q0 + wave*16)*2048);

  // preload tile 0 into regs, stage to buffer 0
  f16x8 kr0 = *(const f16x8*)(ksrc);
  f16x8 kr1 = *(const f16x8*)(ksrc + 8);
  f16x8 vr0 = *(const f16x8*)(vsrc);
  f16x8 vr1 = *(const f16x8*)(vsrc + 8);
  *(f16x8*)&Klds[0][sr][sc]   = kr0;
  *(f16x8*)&Klds[0][sr][sc+8] = kr1;
  *(f16x8*)&Vlds[0][sr][sc]   = vr0;
  *(f16x8*)&Vlds[0][sr][sc+8] = vr1;
  __syncthreads();

  for (int t = 0; t < 32; ++t, base_w += 64u){
    const int buf = t & 1;
    // issue next tile's loads (complete during this tile's compute)
    if (t < 31){
      const f16* ks = ksrc + (long)(t+1)*4096;
      kr0 = *(const f16x8*)ks;
      kr1 = *(const f16x8*)(ks + 8);
      const f16* vs = vsrc + (long)(t+1)*64;
      vr0 = *(const f16x8*)vs;
      vr1 = *(const f16x8*)(vs + 8);
    }

    f32x4 s[4];
    #pragma unroll
    for (int n=0;n<4;n++){ s[n][0]=0.f;s[n][1]=0.f;s[n][2]=0.f;s[n][3]=0.f; }
    __builtin_amdgcn_s_setprio(1);
    #pragma unroll
    for (int n=0;n<4;n++){
      f16x8 kf0 = *(const f16x8*)&Klds[buf][16*n+llo][lhi*8];
      s[n] = __builtin_amdgcn_mfma_f32_16x16x32_f16(qf0, kf0, s[n], 0,0,0);
      f16x8 kf1 = *(const f16x8*)&Klds[buf][16*n+llo][32+lhi*8];
      s[n] = __builtin_amdgcn_mfma_f32_16x16x32_f16(qf1, kf1, s[n], 0,0,0);
    }
    __builtin_amdgcn_s_setprio(0);
    float pmax[4];
    #pragma unroll
    for (int j=0;j<4;j++)
      pmax[j] = fmaxf(fmaxf(s[0][j],s[1][j]), fmaxf(s[2][j],s[3][j]));
    #pragma unroll
    for (int off=1; off<16; off<<=1){
      #pragma unroll
      for (int j=0;j<4;j++) pmax[j] = fmaxf(pmax[j], __shfl_xor(pmax[j], off));
    }
    float esc[4];
    #pragma unroll
    for (int j=0;j<4;j++){
      float mnew = fmaxf(mrun[j], pmax[j]);
      esc[j] = __expf(mrun[j] - mnew);
      mrun[j] = mnew;
    }
    float p[4][4];
    #pragma unroll
    for (int n=0;n<4;n++)
      #pragma unroll
      for (int j=0;j<4;j++)
        p[n][j] = __expf(s[n][j] - mrun[j]);
    #pragma unroll
    for (int n=0;n<4;n++)
      #pragma unroll
      for (int j=0;j<4;j++) O[n][j] *= esc[j];

    // ---- store P (pre-dropout, scaled 1/0.9) + ballot survivor compaction ----
    uint32_t cnt = 0;
    #pragma unroll
    for (int j=0;j<4;j++){
      #pragma unroll
      for (int n=0;n<4;n++){
        float pm = p[n][j]*(1.0f/0.9f);
        bool surv = pm > 0x1.0p-25f;            // (f16)pm != 0
        Plds[wave][lhi*4+j][16*n+llo] = (f16)pm;
        unsigned long long mk = __ballot(surv);
        if (mk){
          uint32_t pre = __builtin_amdgcn_mbcnt_hi((uint32_t)(mk>>32),
                         __builtin_amdgcn_mbcnt_lo((uint32_t)mk, 0u));
          if (surv)
            Idl[wave][cnt + pre] = (unsigned short)((j<<8)|(n<<6)|lane);
          cnt += (uint32_t)__builtin_popcountll(mk);
        }
      }
    }

    // ---- lsum via ones-MFMA on pre-scatter P (rowsum); lsum = 0.9 * Σ pm ----
    {
      f16x8 la0 = *(const f16x8*)&Plds[wave][llo][lhi*8];
      f16x8 la1 = *(const f16x8*)&Plds[wave][llo][32+lhi*8];
      f32x4 lc; lc[0]=0.f; lc[1]=0.f; lc[2]=0.f; lc[3]=0.f;
      __builtin_amdgcn_s_setprio(1);
      lc = __builtin_amdgcn_mfma_f32_16x16x32_f16(la0, ones1, lc, 0,0,0);
      lc = __builtin_amdgcn_mfma_f32_16x16x32_f16(la1, ones1, lc, 0,0,0);
      __builtin_amdgcn_s_setprio(0);
      #pragma unroll
      for (int j=0;j<4;j++) lrun[j] = lrun[j]*esc[j] + 0.9f*lc[j];
    }

    // ---- threefry only for survivors; drops scatter zeros into Plds ----
    for (uint32_t pb = 0; pb < cnt; pb += 64){
      uint32_t idx = pb + (uint32_t)lane;
      if (idx < cnt){
        uint32_t id = (uint32_t)Idl[wave][idx];
        uint32_t jj = (id>>8)&3u, nn = (id>>6)&3u, ln = id & 63u;
        uint32_t i = base_w + (ln>>4)*8192u + jj*2048u + nn*16u + (ln&15u);
        uint32_t bits = tf_bits(i);
        if (bits >= 0xE6666600u)                 // uniform(bits) >= 0.9 -> drop
          Plds[wave][(ln>>4)*4+jj][16*nn+(ln&15u)] = (f16)0;
      }
    }

    f16x8 pa0 = *(const f16x8*)&Plds[wave][llo][lhi*8];
    f16x8 pa1 = *(const f16x8*)&Plds[wave][llo][32+lhi*8];
    __builtin_amdgcn_s_setprio(1);
    #pragma unroll
    for (int n=0;n<4;n++){
      f16x8 vf0 = *(const f16x8*)&Vlds[buf][16*n+llo][lhi*8];
      O[n] = __builtin_amdgcn_mfma_f32_16x16x32_f16(pa0, vf0, O[n], 0,0,0);
      f16x8 vf1 = *(const f16x8*)&Vlds[buf][16*n+llo][32+lhi*8];
      O[n] = __builtin_amdgcn_mfma_f32_16x16x32_f16(pa1, vf1, O[n], 0,0,0);
    }
    __builtin_amdgcn_s_setprio(0);

    // stage next tile into the other buffer; ONE barrier per iteration
    if (t < 31){
      *(f16x8*)&Klds[buf^1][sr][sc]   = kr0;
      *(f16x8*)&Klds[buf^1][sr][sc+8] = kr1;
      *(f16x8*)&Vlds[buf^1][sr][sc]   = vr0;
      *(f16x8*)&Vlds[buf^1][sr][sc+8] = vr1;
    }
    __syncthreads();
  }

  // ---- fused epilogue: out[rows] = (O/l) @ Wo + bo, O staged f16 in Klds[0] ----
  float rl[4];
  #pragma unroll
  for (int j=0;j<4;j++) rl[j] = 1.0f / lrun[j];
  #pragma unroll
  for (int n=0;n<4;n++)
    #pragma unroll
    for (int j=0;j<4;j++)
      Klds[0][wave*16 + lhi*4 + j][16*n + llo] = (f16)(O[n][j]*rl[j]);
  __syncthreads();

  f16x8 af0 = *(const f16x8*)&Klds[0][wave*16 + llo][lhi*8];
  f16x8 af1 = *(const f16x8*)&Klds[0][wave*16 + llo][32 + lhi*8];
  const long robase = (long)bh*2048 + q0 + wave*16 + lhi*4;
  for (int n0 = 0; n0 < 1024; n0 += 16){
    f16x8 b0 = *(const f16x8*)&WoT[(long)(n0+llo)*64 + lhi*8];
    f16x8 b1 = *(const f16x8*)&WoT[(long)(n0+llo)*64 + 32 + lhi*8];
    float bb = bo[n0+llo];
    f32x4 c; c[0]=bb; c[1]=bb; c[2]=bb; c[3]=bb;
    c = __builtin_amdgcn_mfma_f32_16x16x32_f16(af0, b0, c, 0,0,0);
    c = __builtin_amdgcn_mfma_f32_16x16x32_f16(af1, b1, c, 0,0,0);
    #pragma unroll
    for (int j=0;j<4;j++)
      out[(robase + j)*1024 + n0 + llo] = c[j];
  }
}

extern "C" void kernel_launch(void* const* d_in, const int* in_sizes, int n_in,
                              void* d_out, int out_size, void* d_ws, size_t ws_size,
                              hipStream_t stream){
  const float* query = (const float*)d_in[0];
  const float* key   = (const float*)d_in[1];
  const float* value = (const float*)d_in[2];
  const float* Wq = (const float*)d_in[3];
  const float* bq = (const float*)d_in[4];
  const float* Wk = (const float*)d_in[5];
  const float* bk = (const float*)d_in[6];
  const float* Wv = (const float*)d_in[7];
  const float* bv = (const float*)d_in[8];
  const float* Wo = (const float*)d_in[9];
  const float* bo = (const float*)d_in[10];
  float* out = (float*)d_out;

  char* ws = (char*)d_ws;
  f16* qp   = (f16*)(ws);                               // 4 MiB
  f16* kp   = (f16*)(ws + ((size_t)4<<20));             // 4 MiB
  f16* vpT  = (f16*)(ws + ((size_t)8<<20));             // 4 MiB
  f16* WoT  = (f16*)(ws + ((size_t)20<<20));            // 128 KiB

  proj_kernel<0><<<dim3(1024), dim3(256), 0, stream>>>(
      query,key,value,Wq,bq,Wk,bk,Wv,bv,Wo,qp,kp,vpT,WoT);
  proj_kernel<1><<<dim3(768), dim3(256), 0, stream>>>(
      query,key,value,Wq,bq,Wk,bk,Wv,bv,Wo,qp,kp,vpT,WoT);
  flash_kernel<<<dim3(32,16), dim3(256), 0, stream>>>(qp,kp,vpT,WoT,bo,out);
}